// Round 9
// baseline (399.753 us; speedup 1.0000x reference)
//
#include <hip/hip_runtime.h>
#include <hip/hip_bf16.h>

// GAT encoder, 2 layers, N=50000, Et=850000 (800k random + 50k self-loops),
// IN=128, HID=OUT=256, HEADS=8, C=32.
// fp16 activations + MFMA f16 GEMM (128x256 tile; layer-1 converts f32 A in staging
// and carries batched CSR-fill blocks); single-pass no-max softmax+gather with
// per-(edge,head) logit computation (ds_swizzle broadcast) + SGPR-base row gather.
// Self-loops placed deterministically in scan23 (no atomics for them).

#define HEADS 8
#define F 256

typedef _Float16 h8 __attribute__((ext_vector_type(8)));
typedef _Float16 h4 __attribute__((ext_vector_type(4)));
typedef float f4 __attribute__((ext_vector_type(4)));

// ---------------- prep: W1/W2 transpose->fp16 | dst histogram (random edges, int4) ----------------

__global__ void k_prep(const float* __restrict__ W1, _Float16* __restrict__ Wt1,
                       const float* __restrict__ W2, _Float16* __restrict__ Wt2,
                       const int* __restrict__ dst, int Er, int* __restrict__ deg) {
  int b = blockIdx.x, tid = threadIdx.x;
  if (b < 128) {
    Wt1[(size_t)tid * 128 + b] = (_Float16)W1[(size_t)b * F + tid];
  } else if (b < 384) {
    int k = b - 128;
    Wt2[(size_t)tid * 256 + k] = (_Float16)W2[(size_t)k * F + tid];
  } else {
    int nq = Er >> 2;
    for (int q = (b - 384) * 256 + tid; q < nq; q += 512 * 256) {
      int4 d4 = *(const int4*)(dst + (q << 2));
      atomicAdd(&deg[d4.x], 1);
      atomicAdd(&deg[d4.y], 1);
      atomicAdd(&deg[d4.z], 1);
      atomicAdd(&deg[d4.w], 1);
    }
  }
}

// ---------------- CSR build (4-aligned segments, self-loop at slot deg[i]) ----------------

__global__ __launch_bounds__(1024) void k_scan1(const int* __restrict__ deg, int n,
                                                int* __restrict__ rowptr, int* __restrict__ bsum) {
  __shared__ int s[1024];
  int i = blockIdx.x * 1024 + threadIdx.x;
  int v = (i < n) ? ((deg[i] + 4) & ~3) : 0;   // ceil4(deg+1): segment 16B-aligned
  s[threadIdx.x] = v;
  __syncthreads();
  for (int off = 1; off < 1024; off <<= 1) {
    int add = (threadIdx.x >= off) ? s[threadIdx.x - off] : 0;
    __syncthreads();
    s[threadIdx.x] += add;
    __syncthreads();
  }
  if (i < n) rowptr[i] = s[threadIdx.x] - v;
  if (threadIdx.x == 1023) bsum[blockIdx.x] = s[1023];
}

// merged scan2+scan3 + deterministic self-loop placement
__global__ void k_scan23(int n, const int* __restrict__ bsum, const int* __restrict__ deg,
                         int* __restrict__ rowptr, int* __restrict__ rowwork,
                         int* __restrict__ csr) {
  __shared__ int boffs;
  int nbx = blockIdx.x >> 2;
  if (threadIdx.x < 64) {
    int t = threadIdx.x;
    int v = (t < nbx) ? bsum[t] : 0;
#pragma unroll
    for (int off = 32; off; off >>= 1) v += __shfl_xor(v, off, 64);
    if (t == 0) boffs = v;
  }
  __syncthreads();
  int i = blockIdx.x * 256 + threadIdx.x;
  if (i < n) {
    int v = rowptr[i] + boffs;
    rowptr[i] = v;
    rowwork[i] = v;
    csr[v + deg[i]] = i;     // self-loop: last valid slot of the segment
  }
}

// ---------------- MFMA GEMM + fused al epilogue (+ batched CSR-fill blocks) ----------------
// C[M,256] = A[M,K] @ B[K,256]; 128x256 tile, 512 threads / 8 waves.
// AF32: A is f32, converted to fp16 during LDS staging (layer 1).
// FILL: blocks >= gemmBlocks scatter the 800k random edges (4/thread, int4 loads).

template <bool AF32, bool FILL>
__global__ __launch_bounds__(512) void k_gemm(const void* __restrict__ Av,
                                              const _Float16* __restrict__ Bt,
                                              _Float16* __restrict__ C,
                                              const float* __restrict__ a_src,
                                              const float* __restrict__ a_dst,
                                              float* __restrict__ als,
                                              float* __restrict__ ald,
                                              int M, int K,
                                              const int* __restrict__ esrc,
                                              const int* __restrict__ edst,
                                              int Er, int* __restrict__ rowwork,
                                              int* __restrict__ csr, int gemmBlocks) {
  if (FILL && (int)blockIdx.x >= gemmBlocks) {
    int nq = Er >> 2;
    int stride = ((int)gridDim.x - gemmBlocks) * 512;
    for (int q = ((int)blockIdx.x - gemmBlocks) * 512 + threadIdx.x; q < nq; q += stride) {
      int4 d4 = *(const int4*)(edst + (q << 2));
      int4 s4 = *(const int4*)(esrc + (q << 2));
      int p0 = atomicAdd(&rowwork[d4.x], 1);
      int p1 = atomicAdd(&rowwork[d4.y], 1);
      int p2 = atomicAdd(&rowwork[d4.z], 1);
      int p3 = atomicAdd(&rowwork[d4.w], 1);
      csr[p0] = s4.x;
      csr[p1] = s4.y;
      csr[p2] = s4.z;
      csr[p3] = s4.w;
    }
    return;
  }

  __shared__ _Float16 As[128][40];   // +8 pad
  __shared__ _Float16 Bs[256][40];
  int tid = threadIdx.x;
  int lane = tid & 63, w = tid >> 6;
  int wr = w & 1, wc = w >> 1;
  int rowBase = blockIdx.x * 128;
  f4 acc[4][4] = {};

  int arow = tid >> 2, akoff = (tid & 3) * 8;
  int arow_g = min(rowBase + arow, M - 1);
  const _Float16* Ap = (const _Float16*)Av + (size_t)arow_g * K + akoff;
  const float*    Apf = (const float*)Av + (size_t)arow_g * K + akoff;
  int bc = tid >> 1, bkoff = (tid & 1) * 16;
  const _Float16* Bp = Bt + (size_t)bc * K + bkoff;

  int kl = (lane >> 4) * 8;
  int rl = lane & 15;

  int nsteps = K >> 5;
  h8 av;
  float4 af0, af1;
  if (AF32) { af0 = *(const float4*)(Apf); af1 = *(const float4*)(Apf + 4); }
  else av = *(const h8*)(Ap);
  h8 bv0 = *(const h8*)(Bp);
  h8 bv1 = *(const h8*)(Bp + 8);

  for (int s = 0; s < nsteps; ++s) {
    if (AF32) {
      h8 t = {(_Float16)af0.x, (_Float16)af0.y, (_Float16)af0.z, (_Float16)af0.w,
              (_Float16)af1.x, (_Float16)af1.y, (_Float16)af1.z, (_Float16)af1.w};
      *(h8*)&As[arow][akoff] = t;
    } else {
      *(h8*)&As[arow][akoff] = av;
    }
    *(h8*)&Bs[bc][bkoff] = bv0;
    *(h8*)&Bs[bc][bkoff + 8] = bv1;
    __syncthreads();
    if (s + 1 < nsteps) {          // T14: issue next-step loads under MFMA
      int k0 = (s + 1) << 5;
      if (AF32) { af0 = *(const float4*)(Apf + k0); af1 = *(const float4*)(Apf + k0 + 4); }
      else av = *(const h8*)(Ap + k0);
      bv0 = *(const h8*)(Bp + k0);
      bv1 = *(const h8*)(Bp + k0 + 8);
    }
    h8 afr[4], bfr[4];
#pragma unroll
    for (int fi = 0; fi < 4; ++fi) afr[fi] = *(const h8*)&As[wr * 64 + fi * 16 + rl][kl];
#pragma unroll
    for (int fj = 0; fj < 4; ++fj) bfr[fj] = *(const h8*)&Bs[wc * 64 + fj * 16 + rl][kl];
#pragma unroll
    for (int fi = 0; fi < 4; ++fi)
#pragma unroll
      for (int fj = 0; fj < 4; ++fj)
        acc[fi][fj] = __builtin_amdgcn_mfma_f32_16x16x32_f16(afr[fi], bfr[fj], acc[fi][fj], 0, 0, 0);
    __syncthreads();
  }

  int rquad = (lane >> 4) * 4;

#pragma unroll
  for (int fi = 0; fi < 4; ++fi)
#pragma unroll
    for (int fj = 0; fj < 4; ++fj) {
      int col = wc * 64 + fj * 16 + rl;
#pragma unroll
      for (int r = 0; r < 4; ++r) {
        int row = rowBase + wr * 64 + fi * 16 + rquad + r;
        if (row < M) C[(size_t)row * F + col] = (_Float16)acc[fi][fj][r];
      }
    }

  // fused al_s/al_d: wave covers heads wc*2 (fj 0,1) and wc*2+1 (fj 2,3)
  int head0 = wc * 2;
  float as0 = a_src[head0 * 32 + rl],      as1 = a_src[head0 * 32 + 16 + rl];
  float ad0 = a_dst[head0 * 32 + rl],      ad1 = a_dst[head0 * 32 + 16 + rl];
  float cs0 = a_src[head0 * 32 + 32 + rl], cs1 = a_src[head0 * 32 + 48 + rl];
  float cd0 = a_dst[head0 * 32 + 32 + rl], cd1 = a_dst[head0 * 32 + 48 + rl];
#pragma unroll
  for (int fi = 0; fi < 4; ++fi)
#pragma unroll
    for (int r = 0; r < 4; ++r) {
      float v0s = acc[fi][0][r] * as0 + acc[fi][1][r] * as1;
      float v0d = acc[fi][0][r] * ad0 + acc[fi][1][r] * ad1;
      float v1s = acc[fi][2][r] * cs0 + acc[fi][3][r] * cs1;
      float v1d = acc[fi][2][r] * cd0 + acc[fi][3][r] * cd1;
#pragma unroll
      for (int off = 8; off; off >>= 1) {
        v0s += __shfl_xor(v0s, off);
        v0d += __shfl_xor(v0d, off);
        v1s += __shfl_xor(v1s, off);
        v1d += __shfl_xor(v1d, off);
      }
      int row = rowBase + wr * 64 + fi * 16 + rquad + r;
      if (rl == 0 && row < M) {
        als[row * HEADS + head0] = v0s;
        ald[row * HEADS + head0] = v0d;
        als[row * HEADS + head0 + 1] = v1s;
        ald[row * HEADS + head0 + 1] = v1d;
      }
    }
}

// ---------------- single-pass softmax+gather aggregate (+bias, ELU) ----------------
// Wave per node. Lane: hh = lane>>3 (head), sl = lane&7 (edge slot);
// lane owns channels lane*4..lane*4+3 (same head). Per 8-edge batch:
// each lane computes p for ONE (edge,head); ds_swizzle broadcasts p_k to its
// head group; row gather uses readfirstlane SGPR base + constant lane offset.

template <bool F16OUT>
__global__ __launch_bounds__(256) void k_agg(const int* __restrict__ rowptr,
                                             const int* __restrict__ deg,
                                             const int* __restrict__ csr,
                                             const float* __restrict__ al_s,
                                             const float* __restrict__ al_d,
                                             const _Float16* __restrict__ h,
                                             const float* __restrict__ bias,
                                             float* __restrict__ outf,
                                             _Float16* __restrict__ outh,
                                             int n) {
  int tid = threadIdx.x;
  int w = tid >> 6, lane = tid & 63;
  int node = blockIdx.x * 4 + w;
  if (node >= n) return;
  int base = rowptr[node];
  int d = deg[node] + 1;            // random edges + self-loop
  int hh = lane >> 3, sl = lane & 7;
  float alD = al_d[node * HEADS + hh];
  const int* cp = csr + base;
  const _Float16* hl = h + (lane << 2);

  f4 acc = {0.f, 0.f, 0.f, 0.f};
  float sp = 0.f;

  for (int j0 = 0; j0 < d; j0 += 8) {
    int je = j0 + sl;
    int jc = min(je, d - 1);
    int s_lane = cp[jc];
    float e = al_s[s_lane * HEADS + hh] + alD;
    e = (e > 0.f) ? e : 0.2f * e;
    float p = (je < d) ? __expf(e) : 0.f;
    sp += p;
    int4 q0 = *(const int4*)(cp + j0);       // broadcast quads (pad reads safe, unused)
    int4 q1 = *(const int4*)(cp + j0 + 4);
    int pi = __builtin_bit_cast(int, p);
#define EDGE(k, sk) \
    if (j0 + (k) < d) { \
      float pk = __builtin_bit_cast(float, __builtin_amdgcn_ds_swizzle(pi, ((k) << 5) | 0x18)); \
      unsigned sU = (unsigned)__builtin_amdgcn_readfirstlane(sk); \
      h4 v = *(const h4*)(hl + ((size_t)sU << 8)); \
      acc.x += pk * (float)v.x; acc.y += pk * (float)v.y; \
      acc.z += pk * (float)v.z; acc.w += pk * (float)v.w; \
    }
    EDGE(0, q0.x) EDGE(1, q0.y) EDGE(2, q0.z) EDGE(3, q0.w)
    EDGE(4, q1.x) EDGE(5, q1.y) EDGE(6, q1.z) EDGE(7, q1.w)
#undef EDGE
  }

#pragma unroll
  for (int off = 4; off; off >>= 1) sp += __shfl_xor(sp, off);  // reduce 8 slots/head
  float invs = 1.f / (sp + 1e-16f);

  int c0 = lane << 2;
  float4 bv = *(const float4*)&bias[c0];
  float o0 = acc.x * invs + bv.x;
  float o1 = acc.y * invs + bv.y;
  float o2 = acc.z * invs + bv.z;
  float o3 = acc.w * invs + bv.w;
  o0 = (o0 > 0.f) ? o0 : expm1f(o0);
  o1 = (o1 > 0.f) ? o1 : expm1f(o1);
  o2 = (o2 > 0.f) ? o2 : expm1f(o2);
  o3 = (o3 > 0.f) ? o3 : expm1f(o3);
  if (F16OUT) {
    h4 o = {(_Float16)o0, (_Float16)o1, (_Float16)o2, (_Float16)o3};
    *(h4*)&outh[((size_t)node << 8) + c0] = o;
  } else {
    *(float4*)&outf[((size_t)node << 8) + c0] = make_float4(o0, o1, o2, o3);
  }
}

// ---------------- launch ----------------

extern "C" void kernel_launch(void* const* d_in, const int* in_sizes, int n_in,
                              void* d_out, int out_size, void* d_ws, size_t ws_size,
                              hipStream_t stream) {
  const float* x   = (const float*)d_in[0];
  const int*   ei  = (const int*)d_in[1];
  const float* W1  = (const float*)d_in[2];
  const float* a1s = (const float*)d_in[3];
  const float* a1d = (const float*)d_in[4];
  const float* b1  = (const float*)d_in[5];
  const float* W2  = (const float*)d_in[6];
  const float* a2s = (const float*)d_in[7];
  const float* a2d = (const float*)d_in[8];
  const float* b2  = (const float*)d_in[9];

  int n  = in_sizes[0] / 128;   // 50000
  int Et = in_sizes[1] / 2;     // 850000
  int Er = Et - n;              // 800000 random edges; self-loops are the tail
  const int* srcp = ei;
  const int* dstp = ei + Et;

  char* ws = (char*)d_ws;
  auto alloc = [&](size_t bytes) {
    char* p = ws;
    ws += (bytes + 255) & ~(size_t)255;
    return p;
  };
  _Float16* hbuf    = (_Float16*)alloc((size_t)n * F * 2);
  _Float16* Wt1     = (_Float16*)alloc((size_t)128 * F * 2);
  _Float16* Wt2     = (_Float16*)alloc((size_t)F * F * 2);
  float*    als     = (float*)alloc((size_t)n * HEADS * 4);
  float*    ald     = (float*)alloc((size_t)n * HEADS * 4);
  int*      deg     = (int*)alloc((size_t)n * 4);
  int*      rowptr  = (int*)alloc((size_t)(n + 1) * 4);
  int*      rowwork = (int*)alloc((size_t)n * 4);
  int*      bsum    = (int*)alloc(64 * 4);
  int*      csr     = (int*)alloc(((size_t)Et + 4 * (size_t)n) * 4);  // ceil4 segments + slack
  _Float16* out1h   = (_Float16*)d_out;  // layer-1 fp16 staged in d_out
  float*    outF    = (float*)d_out;

  hipMemsetAsync(deg, 0, (size_t)n * 4, stream);

  k_prep<<<384 + 512, 256, 0, stream>>>(W1, Wt1, W2, Wt2, dstp, Er, deg);

  int nb = (n + 1023) / 1024;
  k_scan1<<<nb, 1024, 0, stream>>>(deg, n, rowptr, bsum);
  k_scan23<<<(n + 255) / 256, 256, 0, stream>>>(n, bsum, deg, rowptr, rowwork, csr);

  int gb = (n + 127) / 128;
  int ab = (n + 3) / 4;
  // layer 1: gemm (f32 A, converts in staging) + batched CSR fill riding along
  k_gemm<true, true><<<gb + 512, 512, 0, stream>>>(x, Wt1, hbuf, a1s, a1d, als, ald,
                                                   n, 128, srcp, dstp, Er, rowwork, csr, gb);
  k_agg<true><<<ab, 256, 0, stream>>>(rowptr, deg, csr, als, ald, hbuf, b1, nullptr, out1h, n);
  // layer 2
  k_gemm<false, false><<<gb, 512, 0, stream>>>(out1h, Wt2, hbuf, a2s, a2d, als, ald,
                                               n, 256, nullptr, nullptr, 0, nullptr, nullptr, gb);
  k_agg<false><<<ab, 256, 0, stream>>>(rowptr, deg, csr, als, ald, hbuf, b2, outF, nullptr, n);
}

// Round 11
// 361.444 us; speedup vs baseline: 1.1060x; 1.1060x over previous
//
#include <hip/hip_runtime.h>
#include <hip/hip_bf16.h>

// GAT encoder, 2 layers, N=50000, Et=850000 (800k random + 50k self-loops),
// IN=128, HID=OUT=256, HEADS=8, C=32.
// fp16 activations + MFMA f16 GEMM (128x256 tile, BK=64; layer-1 converts f32 A in
// staging and carries CSR-fill blocks scheduled FIRST); single-pass no-max
// softmax+gather aggregation (round-7 structure: redundant per-lane logits overlap
// the gather loads). Self-loops placed deterministically in scan23.

#define HEADS 8
#define F 256

typedef _Float16 h8 __attribute__((ext_vector_type(8)));
typedef _Float16 h4 __attribute__((ext_vector_type(4)));
typedef float f4 __attribute__((ext_vector_type(4)));

// ---------------- prep: W1/W2 transpose->fp16 | dst histogram (random edges, int4) ----------------

__global__ void k_prep(const float* __restrict__ W1, _Float16* __restrict__ Wt1,
                       const float* __restrict__ W2, _Float16* __restrict__ Wt2,
                       const int* __restrict__ dst, int Er, int* __restrict__ deg) {
  int b = blockIdx.x, tid = threadIdx.x;
  if (b < 128) {
    Wt1[(size_t)tid * 128 + b] = (_Float16)W1[(size_t)b * F + tid];
  } else if (b < 384) {
    int k = b - 128;
    Wt2[(size_t)tid * 256 + k] = (_Float16)W2[(size_t)k * F + tid];
  } else {
    int nq = Er >> 2;
    for (int q = (b - 384) * 256 + tid; q < nq; q += 512 * 256) {
      int4 d4 = *(const int4*)(dst + (q << 2));
      atomicAdd(&deg[d4.x], 1);
      atomicAdd(&deg[d4.y], 1);
      atomicAdd(&deg[d4.z], 1);
      atomicAdd(&deg[d4.w], 1);
    }
  }
}

// ---------------- CSR build (4-aligned segments, self-loop at slot deg[i]) ----------------

__global__ __launch_bounds__(1024) void k_scan1(const int* __restrict__ deg, int n,
                                                int* __restrict__ rowptr, int* __restrict__ bsum) {
  __shared__ int s[1024];
  int i = blockIdx.x * 1024 + threadIdx.x;
  int v = (i < n) ? ((deg[i] + 4) & ~3) : 0;   // ceil4(deg+1): segment 16B-aligned
  s[threadIdx.x] = v;
  __syncthreads();
  for (int off = 1; off < 1024; off <<= 1) {
    int add = (threadIdx.x >= off) ? s[threadIdx.x - off] : 0;
    __syncthreads();
    s[threadIdx.x] += add;
    __syncthreads();
  }
  if (i < n) rowptr[i] = s[threadIdx.x] - v;
  if (threadIdx.x == 1023) bsum[blockIdx.x] = s[1023];
}

// merged scan2+scan3 + deterministic self-loop placement
__global__ void k_scan23(int n, const int* __restrict__ bsum, const int* __restrict__ deg,
                         int* __restrict__ rowptr, int* __restrict__ rowwork,
                         int* __restrict__ csr) {
  __shared__ int boffs;
  int nbx = blockIdx.x >> 2;
  if (threadIdx.x < 64) {
    int t = threadIdx.x;
    int v = (t < nbx) ? bsum[t] : 0;
#pragma unroll
    for (int off = 32; off; off >>= 1) v += __shfl_xor(v, off, 64);
    if (t == 0) boffs = v;
  }
  __syncthreads();
  int i = blockIdx.x * 256 + threadIdx.x;
  if (i < n) {
    int v = rowptr[i] + boffs;
    rowptr[i] = v;
    rowwork[i] = v;
    csr[v + deg[i]] = i;     // self-loop: last valid slot of the segment
  }
}

// ---------------- MFMA GEMM (BK=64) + fused al epilogue (+ CSR-fill blocks first) ----------------
// C[M,256] = A[M,K] @ B[K,256]; 128x256 tile, 512 threads / 8 waves, 64-K steps.
// AF32: A is f32, converted to fp16 during LDS staging (layer 1).
// FILL: blocks [0, fillB) scatter the 800k random edges (4/thread, int4 loads);
//       scheduled first so the atomic tail starts immediately.

template <bool AF32, bool FILL>
__global__ __launch_bounds__(512) void k_gemm(const void* __restrict__ Av,
                                              const _Float16* __restrict__ Bt,
                                              _Float16* __restrict__ C,
                                              const float* __restrict__ a_src,
                                              const float* __restrict__ a_dst,
                                              float* __restrict__ als,
                                              float* __restrict__ ald,
                                              int M, int K,
                                              const int* __restrict__ esrc,
                                              const int* __restrict__ edst,
                                              int Er, int* __restrict__ rowwork,
                                              int* __restrict__ csr, int fillB) {
  if (FILL && (int)blockIdx.x < fillB) {
    int nq = Er >> 2;
    int stride = fillB * 512;
    for (int q = (int)blockIdx.x * 512 + threadIdx.x; q < nq; q += stride) {
      int4 d4 = *(const int4*)(edst + (q << 2));
      int4 s4 = *(const int4*)(esrc + (q << 2));
      int p0 = atomicAdd(&rowwork[d4.x], 1);
      int p1 = atomicAdd(&rowwork[d4.y], 1);
      int p2 = atomicAdd(&rowwork[d4.z], 1);
      int p3 = atomicAdd(&rowwork[d4.w], 1);
      csr[p0] = s4.x;
      csr[p1] = s4.y;
      csr[p2] = s4.z;
      csr[p3] = s4.w;
    }
    return;
  }
  int bid = FILL ? (int)blockIdx.x - fillB : (int)blockIdx.x;

  __shared__ _Float16 As[128][72];   // +8 pad; 144B row stride -> 2-way (free)
  __shared__ _Float16 Bs[256][72];
  int tid = threadIdx.x;
  int lane = tid & 63, w = tid >> 6;
  int wr = w & 1, wc = w >> 1;
  int rowBase = bid * 128;
  f4 acc[4][4] = {};

  int arow = tid >> 2, akoff = (tid & 3) * 16;   // 64 halfs/row over 4 threads
  int arow_g = min(rowBase + arow, M - 1);
  const _Float16* Ap = (const _Float16*)Av + (size_t)arow_g * K + akoff;
  const float*    Apf = (const float*)Av + (size_t)arow_g * K + akoff;
  int bc = tid >> 1, bkoff = (tid & 1) * 32;     // 64 halfs/col over 2 threads
  const _Float16* Bp = Bt + (size_t)bc * K + bkoff;

  int kl = (lane >> 4) * 8;
  int rl = lane & 15;

  int nsteps = K >> 6;   // BK=64
  h8 av0, av1;
  float4 af0, af1, af2, af3;
  if (AF32) {
    af0 = *(const float4*)(Apf);     af1 = *(const float4*)(Apf + 4);
    af2 = *(const float4*)(Apf + 8); af3 = *(const float4*)(Apf + 12);
  } else {
    av0 = *(const h8*)(Ap); av1 = *(const h8*)(Ap + 8);
  }
  h8 bv0 = *(const h8*)(Bp);      h8 bv1 = *(const h8*)(Bp + 8);
  h8 bv2 = *(const h8*)(Bp + 16); h8 bv3 = *(const h8*)(Bp + 24);

  for (int s = 0; s < nsteps; ++s) {
    if (AF32) {
      h8 t0 = {(_Float16)af0.x, (_Float16)af0.y, (_Float16)af0.z, (_Float16)af0.w,
               (_Float16)af1.x, (_Float16)af1.y, (_Float16)af1.z, (_Float16)af1.w};
      h8 t1 = {(_Float16)af2.x, (_Float16)af2.y, (_Float16)af2.z, (_Float16)af2.w,
               (_Float16)af3.x, (_Float16)af3.y, (_Float16)af3.z, (_Float16)af3.w};
      *(h8*)&As[arow][akoff] = t0;
      *(h8*)&As[arow][akoff + 8] = t1;
    } else {
      *(h8*)&As[arow][akoff] = av0;
      *(h8*)&As[arow][akoff + 8] = av1;
    }
    *(h8*)&Bs[bc][bkoff] = bv0;
    *(h8*)&Bs[bc][bkoff + 8] = bv1;
    *(h8*)&Bs[bc][bkoff + 16] = bv2;
    *(h8*)&Bs[bc][bkoff + 24] = bv3;
    __syncthreads();
    if (s + 1 < nsteps) {          // T14: issue next-step loads under MFMA
      int k0 = (s + 1) << 6;
      if (AF32) {
        af0 = *(const float4*)(Apf + k0);     af1 = *(const float4*)(Apf + k0 + 4);
        af2 = *(const float4*)(Apf + k0 + 8); af3 = *(const float4*)(Apf + k0 + 12);
      } else {
        av0 = *(const h8*)(Ap + k0); av1 = *(const h8*)(Ap + k0 + 8);
      }
      bv0 = *(const h8*)(Bp + k0);      bv1 = *(const h8*)(Bp + k0 + 8);
      bv2 = *(const h8*)(Bp + k0 + 16); bv3 = *(const h8*)(Bp + k0 + 24);
    }
#pragma unroll
    for (int kk = 0; kk < 64; kk += 32) {
      h8 afr[4], bfr[4];
#pragma unroll
      for (int fi = 0; fi < 4; ++fi) afr[fi] = *(const h8*)&As[wr * 64 + fi * 16 + rl][kk + kl];
#pragma unroll
      for (int fj = 0; fj < 4; ++fj) bfr[fj] = *(const h8*)&Bs[wc * 64 + fj * 16 + rl][kk + kl];
#pragma unroll
      for (int fi = 0; fi < 4; ++fi)
#pragma unroll
        for (int fj = 0; fj < 4; ++fj)
          acc[fi][fj] = __builtin_amdgcn_mfma_f32_16x16x32_f16(afr[fi], bfr[fj], acc[fi][fj], 0, 0, 0);
    }
    __syncthreads();
  }

  int rquad = (lane >> 4) * 4;

#pragma unroll
  for (int fi = 0; fi < 4; ++fi)
#pragma unroll
    for (int fj = 0; fj < 4; ++fj) {
      int col = wc * 64 + fj * 16 + rl;
#pragma unroll
      for (int r = 0; r < 4; ++r) {
        int row = rowBase + wr * 64 + fi * 16 + rquad + r;
        if (row < M) C[(size_t)row * F + col] = (_Float16)acc[fi][fj][r];
      }
    }

  // fused al_s/al_d: wave covers heads wc*2 (fj 0,1) and wc*2+1 (fj 2,3)
  int head0 = wc * 2;
  float as0 = a_src[head0 * 32 + rl],      as1 = a_src[head0 * 32 + 16 + rl];
  float ad0 = a_dst[head0 * 32 + rl],      ad1 = a_dst[head0 * 32 + 16 + rl];
  float cs0 = a_src[head0 * 32 + 32 + rl], cs1 = a_src[head0 * 32 + 48 + rl];
  float cd0 = a_dst[head0 * 32 + 32 + rl], cd1 = a_dst[head0 * 32 + 48 + rl];
#pragma unroll
  for (int fi = 0; fi < 4; ++fi)
#pragma unroll
    for (int r = 0; r < 4; ++r) {
      float v0s = acc[fi][0][r] * as0 + acc[fi][1][r] * as1;
      float v0d = acc[fi][0][r] * ad0 + acc[fi][1][r] * ad1;
      float v1s = acc[fi][2][r] * cs0 + acc[fi][3][r] * cs1;
      float v1d = acc[fi][2][r] * cd0 + acc[fi][3][r] * cd1;
#pragma unroll
      for (int off = 8; off; off >>= 1) {
        v0s += __shfl_xor(v0s, off);
        v0d += __shfl_xor(v0d, off);
        v1s += __shfl_xor(v1s, off);
        v1d += __shfl_xor(v1d, off);
      }
      int row = rowBase + wr * 64 + fi * 16 + rquad + r;
      if (rl == 0 && row < M) {
        als[row * HEADS + head0] = v0s;
        ald[row * HEADS + head0] = v0d;
        als[row * HEADS + head0 + 1] = v1s;
        ald[row * HEADS + head0 + 1] = v1d;
      }
    }
}

// ---------------- single-pass softmax+gather aggregate (+bias, ELU) ----------------
// Round-7 structure: skip segment-max (logits bounded, exp safe in f32).
// Wave per node; lane owns 4 channels, head hh = lane>>3. All lanes compute
// logits redundantly — this VALU work overlaps the gather loads. No LDS, no syncs.

template <bool F16OUT>
__global__ __launch_bounds__(256) void k_agg(const int* __restrict__ rowptr,
                                             const int* __restrict__ deg,
                                             const int* __restrict__ csr,
                                             const float* __restrict__ al_s,
                                             const float* __restrict__ al_d,
                                             const _Float16* __restrict__ h,
                                             const float* __restrict__ bias,
                                             float* __restrict__ outf,
                                             _Float16* __restrict__ outh,
                                             int n) {
  int tid = threadIdx.x;
  int w = tid >> 6, lane = tid & 63;
  int node = blockIdx.x * 4 + w;
  if (node >= n) return;
  int base = rowptr[node];          // 16B-aligned segment
  int d = deg[node] + 1;            // random edges + self-loop
  int hh = lane >> 3;
  float alD = al_d[node * HEADS + hh];
  const _Float16* hc = h + (lane << 2);
  const int* cp = csr + base;

  f4 acc = {0.f, 0.f, 0.f, 0.f};
  float sp = 0.f;
  int j = 0;
  if (d >= 4) {
    int4 sv = *(const int4*)cp;     // same-addr across lanes -> broadcast
    for (; j + 4 <= d; j += 4) {
      int4 svn = sv;
      if (j + 8 <= d) svn = *(const int4*)(cp + j + 4);   // prefetch next quad
      float e0 = al_s[sv.x * HEADS + hh] + alD;
      float e1 = al_s[sv.y * HEADS + hh] + alD;
      float e2 = al_s[sv.z * HEADS + hh] + alD;
      float e3 = al_s[sv.w * HEADS + hh] + alD;
      e0 = (e0 > 0.f) ? e0 : 0.2f * e0;
      e1 = (e1 > 0.f) ? e1 : 0.2f * e1;
      e2 = (e2 > 0.f) ? e2 : 0.2f * e2;
      e3 = (e3 > 0.f) ? e3 : 0.2f * e3;
      float p0 = __expf(e0), p1 = __expf(e1), p2 = __expf(e2), p3 = __expf(e3);
      h4 v0 = *(const h4*)(hc + ((size_t)sv.x << 8));
      h4 v1 = *(const h4*)(hc + ((size_t)sv.y << 8));
      h4 v2 = *(const h4*)(hc + ((size_t)sv.z << 8));
      h4 v3 = *(const h4*)(hc + ((size_t)sv.w << 8));
      acc.x += p0 * (float)v0.x + p1 * (float)v1.x + p2 * (float)v2.x + p3 * (float)v3.x;
      acc.y += p0 * (float)v0.y + p1 * (float)v1.y + p2 * (float)v2.y + p3 * (float)v3.y;
      acc.z += p0 * (float)v0.z + p1 * (float)v1.z + p2 * (float)v2.z + p3 * (float)v3.z;
      acc.w += p0 * (float)v0.w + p1 * (float)v1.w + p2 * (float)v2.w + p3 * (float)v3.w;
      sp += p0 + p1 + p2 + p3;
      sv = svn;
    }
  }
  for (; j < d; ++j) {
    int s = cp[j];
    float e = al_s[s * HEADS + hh] + alD;
    e = (e > 0.f) ? e : 0.2f * e;
    float p = __expf(e);
    h4 v = *(const h4*)(hc + ((size_t)s << 8));
    acc.x += p * (float)v.x;
    acc.y += p * (float)v.y;
    acc.z += p * (float)v.z;
    acc.w += p * (float)v.w;
    sp += p;
  }

  float invs = 1.f / (sp + 1e-16f);
  int c0 = lane << 2;
  float4 bv = *(const float4*)&bias[c0];
  float o0 = acc.x * invs + bv.x;
  float o1 = acc.y * invs + bv.y;
  float o2 = acc.z * invs + bv.z;
  float o3 = acc.w * invs + bv.w;
  o0 = (o0 > 0.f) ? o0 : expm1f(o0);
  o1 = (o1 > 0.f) ? o1 : expm1f(o1);
  o2 = (o2 > 0.f) ? o2 : expm1f(o2);
  o3 = (o3 > 0.f) ? o3 : expm1f(o3);
  if (F16OUT) {
    h4 o = {(_Float16)o0, (_Float16)o1, (_Float16)o2, (_Float16)o3};
    *(h4*)&outh[((size_t)node << 8) + c0] = o;
  } else {
    *(float4*)&outf[((size_t)node << 8) + c0] = make_float4(o0, o1, o2, o3);
  }
}

// ---------------- launch ----------------

extern "C" void kernel_launch(void* const* d_in, const int* in_sizes, int n_in,
                              void* d_out, int out_size, void* d_ws, size_t ws_size,
                              hipStream_t stream) {
  const float* x   = (const float*)d_in[0];
  const int*   ei  = (const int*)d_in[1];
  const float* W1  = (const float*)d_in[2];
  const float* a1s = (const float*)d_in[3];
  const float* a1d = (const float*)d_in[4];
  const float* b1  = (const float*)d_in[5];
  const float* W2  = (const float*)d_in[6];
  const float* a2s = (const float*)d_in[7];
  const float* a2d = (const float*)d_in[8];
  const float* b2  = (const float*)d_in[9];

  int n  = in_sizes[0] / 128;   // 50000
  int Et = in_sizes[1] / 2;     // 850000
  int Er = Et - n;              // 800000 random edges; self-loops are the tail
  const int* srcp = ei;
  const int* dstp = ei + Et;

  char* ws = (char*)d_ws;
  auto alloc = [&](size_t bytes) {
    char* p = ws;
    ws += (bytes + 255) & ~(size_t)255;
    return p;
  };
  _Float16* hbuf    = (_Float16*)alloc((size_t)n * F * 2);
  _Float16* Wt1     = (_Float16*)alloc((size_t)128 * F * 2);
  _Float16* Wt2     = (_Float16*)alloc((size_t)F * F * 2);
  float*    als     = (float*)alloc((size_t)n * HEADS * 4);
  float*    ald     = (float*)alloc((size_t)n * HEADS * 4);
  int*      deg     = (int*)alloc((size_t)n * 4);
  int*      rowptr  = (int*)alloc((size_t)(n + 1) * 4);
  int*      rowwork = (int*)alloc((size_t)n * 4);
  int*      bsum    = (int*)alloc(64 * 4);
  int*      csr     = (int*)alloc(((size_t)Et + 4 * (size_t)n) * 4);  // ceil4 segments + slack
  _Float16* out1h   = (_Float16*)d_out;  // layer-1 fp16 staged in d_out
  float*    outF    = (float*)d_out;

  hipMemsetAsync(deg, 0, (size_t)n * 4, stream);

  k_prep<<<384 + 512, 256, 0, stream>>>(W1, Wt1, W2, Wt2, dstp, Er, deg);

  int nb = (n + 1023) / 1024;
  k_scan1<<<nb, 1024, 0, stream>>>(deg, n, rowptr, bsum);
  k_scan23<<<(n + 255) / 256, 256, 0, stream>>>(n, bsum, deg, rowptr, rowwork, csr);

  int gb = (n + 127) / 128;
  int ab = (n + 3) / 4;
  int fillB = 512;
  // layer 1: fill blocks first (atomic scatter starts immediately), gemm blocks after
  k_gemm<true, true><<<fillB + gb, 512, 0, stream>>>(x, Wt1, hbuf, a1s, a1d, als, ald,
                                                     n, 128, srcp, dstp, Er, rowwork, csr, fillB);
  k_agg<true><<<ab, 256, 0, stream>>>(rowptr, deg, csr, als, ald, hbuf, b1, nullptr, out1h, n);
  // layer 2
  k_gemm<false, false><<<gb, 512, 0, stream>>>(out1h, Wt2, hbuf, a2s, a2d, als, ald,
                                               n, 256, nullptr, nullptr, 0, nullptr, nullptr, 0);
  k_agg<false><<<ab, 256, 0, stream>>>(rowptr, deg, csr, als, ald, hbuf, b2, outF, nullptr, n);
}